// Round 1
// baseline (7847.304 us; speedup 1.0000x reference)
//
#include <hip/hip_runtime.h>
#include <cstddef>

#define BLK 256

// ============================ weight transpose ============================
// W[O][I][KH] -> Wt[KH][I][O]
__global__ void wtrans_k(const float* __restrict__ W, float* __restrict__ Wt,
                         int O, int I, int KH) {
    int idx = blockIdx.x * BLK + threadIdx.x;
    int total = O * I * KH;
    if (idx >= total) return;
    int o = idx % O;
    int r = idx / O;
    int i = r % I;
    int dh = r / I;
    Wt[idx] = W[(o * I + i) * KH + dh];
}

// ============================ input gather ============================
// x[B,1,5,127] (batch chunk) -> xt [1][5][cb][127]  (CHBW)
__global__ void xin_k(const float* __restrict__ x, float* __restrict__ xt,
                      int b0, int cb) {
    int idx = blockIdx.x * BLK + threadIdx.x;
    int total = 5 * cb * 127;
    if (idx >= total) return;
    int w = idx % 127;
    int r = idx / 127;
    int b = r % cb;
    int h = r / cb;
    xt[idx] = x[(size_t)(b0 + b) * 635 + h * 127 + w];
}

// ============================ output scatter ============================
// v2 [512][3][cb][18] (CHBW) -> out[B,512,3,18] (natural)
__global__ void xout_k(const float* __restrict__ v, float* __restrict__ out,
                       int b0, int cb) {
    int idx = blockIdx.x * BLK + threadIdx.x;
    int total = cb * 512 * 3 * 18;
    if (idx >= total) return;
    int w = idx % 18; int r = idx / 18;
    int h = r % 3; r /= 3;
    int o = r % 512; int b = r / 512;
    out[(((size_t)(b0 + b) * 512 + o) * 3 + h) * 18 + w] =
        v[(((size_t)o * 3 + h) * cb + b) * 18 + w];
}

// ============================ conv0a: I=1,KH=3,P=1,O=5,HIN=5 ============================
// natural weights W[o][0][dh]; in [1][5][N], out [5][5][N]
__global__ void conv0a_k(const float* __restrict__ in, const float* __restrict__ W,
                         const float* __restrict__ bias, float* __restrict__ out, int N) {
    int n = blockIdx.x * BLK + threadIdx.x;
    if (n >= N) return;
    float xv[5];
#pragma unroll
    for (int h = 0; h < 5; ++h) xv[h] = in[(size_t)h * N + n];
#pragma unroll
    for (int o = 0; o < 5; ++o) {
        float w0 = W[o * 3 + 0], w1 = W[o * 3 + 1], w2 = W[o * 3 + 2];
        float bv = bias[o];
#pragma unroll
        for (int h = 0; h < 5; ++h) {
            float acc = bv + w1 * xv[h];
            if (h > 0) acc += w0 * xv[h - 1];
            if (h < 4) acc += w2 * xv[h + 1];
            out[((size_t)o * 5 + h) * N + n] = acc;
        }
    }
}

// ============================ conv0c: 1x1, I=1, O=25 ============================
// y0[o][h][n] = W[o]*t3[h][n] + b[o];  idx runs over [5][N] = N5 elements
__global__ void conv0c_k(const float* __restrict__ in, const float* __restrict__ W,
                         const float* __restrict__ bias, float* __restrict__ out, int N5) {
    int idx = blockIdx.x * BLK + threadIdx.x;
    if (idx >= N5) return;
    float v = in[idx];
#pragma unroll
    for (int o = 0; o < 25; ++o)
        out[(size_t)o * N5 + idx] = W[o] * v + bias[o];
}

// ============================ generic conv (CHBW GEMM) ============================
// in  [I][HIN][N], Wt [KH][I][O], out [O][HOUT][N]; N = cb*W (w never mixed)
// block: 16 o-lanes x 16 n-lanes; thread tile TO x 8; o = o0 + to*TO + a
template<int I, int O, int KH, int PAD, int HIN, int TO, int IC, bool ADD>
__global__ __launch_bounds__(256)
void conv_k(const float* __restrict__ in, const float* __restrict__ Wt,
            const float* __restrict__ bias, const float* __restrict__ add,
            float* __restrict__ out, int N) {
    constexpr int HOUT = HIN - KH + 1 + 2 * PAD;
    constexpr int OT = 16 * TO;
    __shared__ __align__(16) float Xs[IC][128];
    __shared__ __align__(16) float As[IC][OT];
    const int n0 = blockIdx.x * 128;
    const int h  = blockIdx.y;
    const int o0 = blockIdx.z * OT;
    const int t  = threadIdx.x;
    const int to = t >> 4;    // 0..15
    const int tn = t & 15;    // 0..15

    float acc[TO][8];
#pragma unroll
    for (int a = 0; a < TO; ++a)
#pragma unroll
        for (int j = 0; j < 8; ++j) acc[a][j] = 0.f;

#pragma unroll
    for (int dh = 0; dh < KH; ++dh) {
        const int hp = h + dh - PAD;
        if (hp < 0 || hp >= HIN) continue;
        const float* __restrict__ inh = in + (size_t)hp * N;
        const float* __restrict__ Wd  = Wt + (size_t)dh * I * O;
        for (int k0 = 0; k0 < I; k0 += IC) {
            __syncthreads();
            for (int e = t; e < IC * 128; e += BLK) {
                const int kk = e >> 7, j = e & 127;
                const int n = n0 + j;
                Xs[kk][j] = (n < N) ? inh[(size_t)(k0 + kk) * HIN * N + n] : 0.f;
            }
            for (int e = t; e < IC * OT; e += BLK) {
                const int kk = e / OT, oo = e % OT;
                const int o = o0 + oo;
                As[kk][oo] = (o < O) ? Wd[(size_t)(k0 + kk) * O + o] : 0.f;
            }
            __syncthreads();
            for (int kk = 0; kk < IC; ++kk) {
                float xr[8];
#pragma unroll
                for (int jj = 0; jj < 2; ++jj)
#pragma unroll
                    for (int j = 0; j < 4; ++j)
                        xr[jj * 4 + j] = Xs[kk][jj * 64 + tn * 4 + j];
#pragma unroll
                for (int a = 0; a < TO; ++a) {
                    const float wv = As[kk][to * TO + a];
#pragma unroll
                    for (int j = 0; j < 8; ++j) acc[a][j] += wv * xr[j];
                }
            }
        }
    }
#pragma unroll
    for (int a = 0; a < TO; ++a) {
        const int o = o0 + to * TO + a;
        if (o >= O) continue;
        const float bv = bias[o];
        const size_t rb = ((size_t)o * HOUT + h) * N;
#pragma unroll
        for (int jj = 0; jj < 2; ++jj)
#pragma unroll
            for (int j = 0; j < 4; ++j) {
                const int n = n0 + jj * 64 + tn * 4 + j;
                if (n < N) {
                    float v = acc[a][jj * 4 + j] + bv;
                    if (ADD) v += add[rb + n];
                    out[rb + n] = v;
                }
            }
    }
}

template<int I, int O, int KH, int PAD, int HIN, int TO, int IC, bool ADD>
static inline void conv_launch(const float* in, const float* Wt, const float* bias,
                               const float* add, float* out, int N, hipStream_t s) {
    constexpr int HOUT = HIN - KH + 1 + 2 * PAD;
    constexpr int OT = 16 * TO;
    dim3 g((N + 127) / 128, HOUT, (O + OT - 1) / OT);
    conv_k<I, O, KH, PAD, HIN, TO, IC, ADD><<<g, BLK, 0, s>>>(in, Wt, bias, add, out, N);
}

// ============================ semi-linear (GEMM over last axis) ============================
// in [N rows][K], Wt [K][O], out [N][O]
// block: 16 o-lanes (lo, store-coalesced) x 16 n-lanes (ln); thread tile TO x 4
template<int K, int O, int TO, bool RELU>
__global__ __launch_bounds__(256)
void lin_k(const float* __restrict__ in, const float* __restrict__ Wt,
           const float* __restrict__ bias, float* __restrict__ out, int N) {
    constexpr int OT = 16 * TO;
    constexpr int IC = 32;
    __shared__ float Xs[IC][65];
    __shared__ float As[IC][OT];
    const int n0 = blockIdx.x * 64;
    const int t = threadIdx.x;
    const int lo = t & 15;   // o-lane
    const int ln = t >> 4;   // n-lane
    float acc[TO][4];
#pragma unroll
    for (int a = 0; a < TO; ++a)
#pragma unroll
        for (int j = 0; j < 4; ++j) acc[a][j] = 0.f;

    for (int k0 = 0; k0 < K; k0 += IC) {
        __syncthreads();
        {
            const int kk = t & 31;
            const int rb = t >> 5;   // 0..7
            const int k = k0 + kk;
#pragma unroll
            for (int p = 0; p < 8; ++p) {
                const int r = rb + 8 * p;
                const int n = n0 + r;
                Xs[kk][r] = (n < N && k < K) ? in[(size_t)n * K + k] : 0.f;
            }
        }
        for (int e = t; e < IC * OT; e += BLK) {
            const int kk = e / OT, oo = e % OT;
            const int k = k0 + kk;
            As[kk][oo] = (k < K && oo < O) ? Wt[(size_t)k * O + oo] : 0.f;
        }
        __syncthreads();
        for (int kk = 0; kk < IC; ++kk) {
            float xr[4];
#pragma unroll
            for (int j = 0; j < 4; ++j) xr[j] = Xs[kk][ln * 4 + j];
#pragma unroll
            for (int a = 0; a < TO; ++a) {
                const float wv = As[kk][lo + 16 * a];
#pragma unroll
                for (int j = 0; j < 4; ++j) acc[a][j] += wv * xr[j];
            }
        }
    }
#pragma unroll
    for (int a = 0; a < TO; ++a) {
        const int o = lo + 16 * a;
        if (o >= O) continue;
        const float bv = bias[o];
#pragma unroll
        for (int j = 0; j < 4; ++j) {
            const int n = n0 + ln * 4 + j;
            if (n < N) {
                float v = acc[a][j] + bv;
                if (RELU) v = fmaxf(v, 0.f);
                out[(size_t)n * O + o] = v;
            }
        }
    }
}

template<int K, int O, int TO, bool RELU>
static inline void lin_launch(const float* in, const float* Wt, const float* bias,
                              float* out, int N, hipStream_t s) {
    dim3 g((N + 63) / 64);
    lin_k<K, O, TO, RELU><<<g, BLK, 0, s>>>(in, Wt, bias, out, N);
}

// ============================ host ============================
extern "C" void kernel_launch(void* const* d_in, const int* in_sizes, int n_in,
                              void* d_out, int out_size, void* d_ws, size_t ws_size,
                              hipStream_t stream) {
    const float* x   = (const float*)d_in[0];
    const float* W0a = (const float*)d_in[1];  const float* b0a = (const float*)d_in[2];
    const float* Wl0 = (const float*)d_in[3];  const float* bl0 = (const float*)d_in[4];
    const float* W0b = (const float*)d_in[5];  const float* b0b = (const float*)d_in[6];
    const float* Wr0 = (const float*)d_in[7];  const float* br0 = (const float*)d_in[8];
    const float* W0c = (const float*)d_in[9];  const float* b0c = (const float*)d_in[10];
    const float* W1  = (const float*)d_in[11]; const float* b1  = (const float*)d_in[12];
    const float* Wl1 = (const float*)d_in[13]; const float* bl1 = (const float*)d_in[14];
    const float* W2  = (const float*)d_in[15]; const float* b2  = (const float*)d_in[16];
    const float* Wra = (const float*)d_in[17]; const float* bra = (const float*)d_in[18];
    const float* Wa  = (const float*)d_in[19]; const float* ba  = (const float*)d_in[20];
    const float* W3  = (const float*)d_in[21]; const float* b3  = (const float*)d_in[22];
    const float* Wl2 = (const float*)d_in[23]; const float* bl2 = (const float*)d_in[24];
    const float* W4  = (const float*)d_in[25]; const float* b4  = (const float*)d_in[26];
    const float* Wrb = (const float*)d_in[27]; const float* brb = (const float*)d_in[28];
    const float* Wb  = (const float*)d_in[29]; const float* bb  = (const float*)d_in[30];
    float* outp = (float*)d_out;

    const int B = in_sizes[0] / 635;   // 1024

    // ---- transposed-weight region (floats), 64-float aligned slots
    size_t cur = 0;
    auto alloc = [&](size_t f) { size_t o = cur; cur = (cur + f + 63) & ~(size_t)63; return o; };
    const size_t o_W0b = alloc(375),    o_W1 = alloc(5625),  o_Wa = alloc(3750),
                 o_W2  = alloc(33750),  o_W3 = alloc(90000), o_W4 = alloc(307200),
                 o_Wb  = alloc(230400),
                 o_Wl0 = alloc(10287),  o_Wl1 = alloc(3321), o_Wl2 = alloc(738),
                 o_Wr0 = alloc(10287),  o_Wra = alloc(3321), o_Wrb = alloc(738);
    const size_t wt_end = cur;

    // ---- per-chunk activation sizes (floats per batch element)
    static const size_t m[16] = {635, 3175, 2025, 405, 10125, 10125, 30375, 15375,
                                 5125, 30750, 30750, 49200, 21600, 13500, 27648, 27648};
    auto chunk_floats = [&](int cbx) -> size_t {
        size_t s = 0;
        for (int i = 0; i < 16; ++i) s += ((m[i] * (size_t)cbx) + 63) & ~(size_t)63;
        return s;
    };
    int CB = 0;
    for (int c = 1024; c >= 8; c >>= 1) {
        if (c > B || (B % c) != 0) continue;
        if ((wt_end + chunk_floats(c)) * 4 <= ws_size) { CB = c; break; }
    }
    if (!CB) return;  // workspace too small even for cb=8

    float* wsf = (float*)d_ws;
    float* abase = wsf + wt_end;
    size_t c2 = 0;
    auto ab = [&](size_t f) { float* p = abase + c2; c2 = (c2 + f + 63) & ~(size_t)63; return p; };
    const int cb = CB;
    float *xt = ab(m[0]*cb),  *t0 = ab(m[1]*cb),  *t1 = ab(m[2]*cb),  *t3 = ab(m[3]*cb),
          *y0 = ab(m[4]*cb),  *x1 = ab(m[5]*cb),  *u0 = ab(m[6]*cb),  *u1 = ab(m[7]*cb),
          *u3 = ab(m[8]*cb),  *y1 = ab(m[9]*cb),  *x2 = ab(m[10]*cb), *v0 = ab(m[11]*cb),
          *v1 = ab(m[12]*cb), *v3 = ab(m[13]*cb), *y2 = ab(m[14]*cb), *v2 = ab(m[15]*cb);

    // ---- weight transposes (every call: ws is re-poisoned by harness)
    auto wt = [&](const float* src, size_t off, int O, int I, int KH) {
        int tot = O * I * KH;
        wtrans_k<<<(tot + BLK - 1) / BLK, BLK, 0, stream>>>(src, wsf + off, O, I, KH);
    };
    wt(W0b, o_W0b, 25, 5, 3);    wt(W1, o_W1, 75, 25, 3);   wt(Wa, o_Wa, 150, 25, 1);
    wt(W2, o_W2, 150, 75, 3);    wt(W3, o_W3, 300, 150, 2); wt(W4, o_W4, 512, 300, 2);
    wt(Wb, o_Wb, 512, 150, 3);
    wt(Wl0, o_Wl0, 81, 127, 1);  wt(Wl1, o_Wl1, 41, 81, 1); wt(Wl2, o_Wl2, 18, 41, 1);
    wt(Wr0, o_Wr0, 81, 127, 1);  wt(Wra, o_Wra, 41, 81, 1); wt(Wrb, o_Wrb, 18, 41, 1);

    for (int b0 = 0; b0 < B; b0 += cb) {
        const int N127 = cb * 127, N81 = cb * 81, N41 = cb * 41, N18 = cb * 18;

        xin_k<<<(5 * N127 + BLK - 1) / BLK, BLK, 0, stream>>>(x, xt, b0, cb);
        // block 0
        conv0a_k<<<(N127 + BLK - 1) / BLK, BLK, 0, stream>>>(xt, W0a, b0a, t0, N127);
        lin_launch<127, 81, 6, true >(t0, wsf + o_Wl0, bl0, t1, 25 * cb, stream);
        lin_launch<127, 81, 6, false>(xt, wsf + o_Wr0, br0, t3, 5 * cb, stream);
        conv0c_k<<<(5 * N81 + BLK - 1) / BLK, BLK, 0, stream>>>(t3, W0c, b0c, y0, 5 * N81);
        conv_launch<5, 25, 3, 1, 5, 2, 5, true >(t1, wsf + o_W0b, b0b, y0, x1, N81, stream);
        // block 1
        conv_launch<25, 75, 3, 1, 5, 5, 25, false>(x1, wsf + o_W1, b1, nullptr, u0, N81, stream);
        lin_launch<81, 41, 3, true >(u0, wsf + o_Wl1, bl1, u1, 375 * cb, stream);
        lin_launch<81, 41, 3, false>(x1, wsf + o_Wra, bra, u3, 125 * cb, stream);
        conv_launch<25, 150, 1, 0, 5, 5, 25, false>(u3, wsf + o_Wa, ba, nullptr, y1, N41, stream);
        conv_launch<75, 150, 3, 1, 5, 5, 25, true >(u1, wsf + o_W2, b2, y1, x2, N41, stream);
        // block 2
        conv_launch<150, 300, 2, 0, 5, 5, 30, false>(x2, wsf + o_W3, b3, nullptr, v0, N41, stream);
        lin_launch<41, 18, 2, true >(v0, wsf + o_Wl2, bl2, v1, 1200 * cb, stream);
        lin_launch<41, 18, 2, false>(x2, wsf + o_Wrb, brb, v3, 750 * cb, stream);
        conv_launch<150, 512, 3, 0, 5, 8, 30, false>(v3, wsf + o_Wb, bb, nullptr, y2, N18, stream);
        conv_launch<300, 512, 2, 0, 4, 8, 30, true >(v1, wsf + o_W4, b4, y2, v2, N18, stream);
        xout_k<<<(cb * 27648 + BLK - 1) / BLK, BLK, 0, stream>>>(v2, outp, b0, cb);
    }
}

// Round 4
// 2853.871 us; speedup vs baseline: 2.7497x; 2.7497x over previous
//
#include <hip/hip_runtime.h>
#include <cstddef>

#define BLK 256

// ======================= weight transform =======================
// W[O][I][KH] (natural, w-kernel dim 1 dropped) -> Wt[KH][I][Mpad], zero-padded in O
__global__ void wtrans_k(const float* __restrict__ W, float* __restrict__ Wt,
                         int O, int I, int KH, int Mpad) {
    int idx = blockIdx.x * BLK + threadIdx.x;
    int total = KH * I * Mpad;
    if (idx >= total) return;
    int o = idx % Mpad;
    int r = idx / Mpad;
    int i = r % I;
    int dh = r / I;
    Wt[idx] = (o < O) ? W[(o * I + i) * KH + dh] : 0.f;
}

// ======================= generic transpose =======================
// in: P x Q (row-major). out: Q x P with out[q][p] = in[p][q]. P must be mult of 64.
__global__ __launch_bounds__(256)
void transpose_k(const float* __restrict__ in, float* __restrict__ out, int P, int Q) {
    __shared__ float tile[64][65];
    const int p0 = blockIdx.y * 64, q0 = blockIdx.x * 64;
    const int j = threadIdx.x & 63, i4 = threadIdx.x >> 6;
#pragma unroll
    for (int ii = 0; ii < 16; ++ii) {
        int i = i4 + 4 * ii;
        int q = q0 + j;
        tile[i][j] = (q < Q) ? in[(size_t)(p0 + i) * Q + q] : 0.f;
    }
    __syncthreads();
#pragma unroll
    for (int ii = 0; ii < 16; ++ii) {
        int a = i4 + 4 * ii;
        if (q0 + a < Q) out[(size_t)(q0 + a) * P + p0 + j] = tile[j][a];
    }
}

// ======================= conv0a: I=1,KH=3,P=1,O=5 =======================
// xt [5][N], W natural [5][1][3], out t0 [5][5][N]   (N = 127*cb)
__global__ void conv0a_k(const float* __restrict__ xt, const float* __restrict__ W,
                         const float* __restrict__ bias, float* __restrict__ out, int N) {
    int n = blockIdx.x * BLK + threadIdx.x;
    if (n >= N) return;
    float xv[5];
#pragma unroll
    for (int h = 0; h < 5; ++h) xv[h] = xt[(size_t)h * N + n];
#pragma unroll
    for (int o = 0; o < 5; ++o) {
        float w0 = W[o * 3 + 0], w1 = W[o * 3 + 1], w2 = W[o * 3 + 2];
        float bv = bias[o];
#pragma unroll
        for (int h = 0; h < 5; ++h) {
            float acc = bv + w1 * xv[h];
            if (h > 0) acc += w0 * xv[h - 1];
            if (h < 4) acc += w2 * xv[h + 1];
            out[((size_t)o * 5 + h) * N + n] = acc;
        }
    }
}

// ======================= conv0c: 1x1, I=1 -> O=25 =======================
__global__ void conv0c_k(const float* __restrict__ in, const float* __restrict__ W,
                         const float* __restrict__ bias, float* __restrict__ out, int N5) {
    int idx = blockIdx.x * BLK + threadIdx.x;
    if (idx >= N5) return;
    float v = in[idx];
#pragma unroll
    for (int o = 0; o < 25; ++o)
        out[(size_t)o * N5 + idx] = W[o] * v + bias[o];
}

// ======================= generic GEMM (conv + semi-linear) =======================
// out[m][z][n] (index m*outMs + z*zsOut + n) =
//   sum_dh sum_k A[dh][k][m] * in[k*ksIn + hp*zsIn + n],  hp = z + dh - PAD
// + bias[m] (+ add) (relu)
// lin: KH=1, PAD=0 => hp = z (batched GEMM over z slabs).
template<int KH, int PAD, int TO, bool ADD, bool RELU>
__global__ __launch_bounds__(256)
void gemm_k(const float* __restrict__ in, const float* __restrict__ A,
            const float* __restrict__ bias, const float* __restrict__ add,
            float* __restrict__ out,
            int K, int Mpad, int Mreal, int N, int HIN,
            int ksIn, int zsIn, int zsOut, int outMs) {
    constexpr int BM = 16 * TO;
    constexpr int BN = 128;
    constexpr int IC = 8;
    __shared__ __align__(16) float Xs[IC][BN];
    __shared__ __align__(16) float As[IC][BM];
    const int n0 = blockIdx.x * BN;
    const int z  = blockIdx.y;
    const int m0 = blockIdx.z * BM;
    const int t  = threadIdx.x;
    const int tn = t & 15, to = t >> 4;
    const bool fullN = (n0 + BN <= N);

    const int xk = t >> 5;            // X staging: row 0..7
    const int xj = (t & 31) * 4;      // X staging: col
    constexpr int AV = IC * BM / 4;   // float4 count for A staging
    const int ak = t / (BM / 4);
    const int aj = (t % (BM / 4)) * 4;

    float acc[TO][8];
#pragma unroll
    for (int a = 0; a < TO; ++a)
#pragma unroll
        for (int j = 0; j < 8; ++j) acc[a][j] = 0.f;

#pragma unroll
    for (int dh = 0; dh < KH; ++dh) {
        const int hp = z + dh - PAD;
        if (hp < 0 || hp >= HIN) continue;
        const float* __restrict__ inz = in + (size_t)hp * zsIn;
        const float* __restrict__ Ad  = A + (size_t)dh * K * Mpad;
        for (int k0 = 0; k0 < K; k0 += IC) {
            __syncthreads();
            {   // stage X: IC x BN
                const int k = k0 + xk;
                float4 v = make_float4(0.f, 0.f, 0.f, 0.f);
                if (k < K) {
                    const float* p = inz + (size_t)k * ksIn + n0 + xj;
                    if (fullN) v = *(const float4*)p;
                    else {
                        float tmp[4] = {0.f, 0.f, 0.f, 0.f};
#pragma unroll
                        for (int u = 0; u < 4; ++u)
                            if (n0 + xj + u < N) tmp[u] = p[u];
                        v = make_float4(tmp[0], tmp[1], tmp[2], tmp[3]);
                    }
                }
                *(float4*)&Xs[xk][xj] = v;
            }
            if (t < AV) {  // stage A: IC x BM (weights are zero-padded to Mpad)
                const int k = k0 + ak;
                float4 v = make_float4(0.f, 0.f, 0.f, 0.f);
                if (k < K) v = *(const float4*)(Ad + (size_t)k * Mpad + m0 + aj);
                *(float4*)&As[ak][aj] = v;
            }
            __syncthreads();
#pragma unroll
            for (int kk = 0; kk < IC; ++kk) {
                float xr[8];
                *(float4*)&xr[0] = *(const float4*)&Xs[kk][tn * 4];
                *(float4*)&xr[4] = *(const float4*)&Xs[kk][64 + tn * 4];
                float ar[TO];
                if constexpr (TO % 4 == 0) {
#pragma unroll
                    for (int g = 0; g < TO / 4; ++g)
                        *(float4*)&ar[g * 4] = *(const float4*)&As[kk][g * 64 + to * 4];
                } else {
#pragma unroll
                    for (int a = 0; a < TO; ++a) ar[a] = As[kk][to + 16 * a];
                }
#pragma unroll
                for (int a = 0; a < TO; ++a)
#pragma unroll
                    for (int j = 0; j < 8; ++j)
                        acc[a][j] = fmaf(ar[a], xr[j], acc[a][j]);
            }
        }
    }

    const size_t zo = (size_t)z * zsOut + n0;
#pragma unroll
    for (int a = 0; a < TO; ++a) {
        int mi;
        if constexpr (TO % 4 == 0) mi = m0 + (a / 4) * 64 + to * 4 + (a % 4);
        else mi = m0 + to + 16 * a;
        if (mi >= Mreal) continue;
        const float bv = bias[mi];
        const size_t rb = (size_t)mi * outMs + zo;
#pragma unroll
        for (int jj = 0; jj < 2; ++jj) {
            const int nb = jj * 64 + tn * 4;
            float v[4];
#pragma unroll
            for (int u = 0; u < 4; ++u) v[u] = acc[a][jj * 4 + u] + bv;
            if (fullN) {
                if (ADD) {
                    float4 w = *(const float4*)(add + rb + nb);
                    v[0] += w.x; v[1] += w.y; v[2] += w.z; v[3] += w.w;
                }
                if (RELU)
#pragma unroll
                    for (int u = 0; u < 4; ++u) v[u] = fmaxf(v[u], 0.f);
                *(float4*)(out + rb + nb) = make_float4(v[0], v[1], v[2], v[3]);
            } else {
#pragma unroll
                for (int u = 0; u < 4; ++u) {
                    if (n0 + nb + u < N) {
                        float vv = v[u];
                        if (ADD) vv += add[rb + nb + u];
                        if (RELU) vv = fmaxf(vv, 0.f);
                        out[rb + nb + u] = vv;
                    }
                }
            }
        }
    }
}

template<int KH, int PAD, int TO, bool ADD, bool RELU>
static inline void gemm_launch(const float* in, const float* A, const float* bias,
                               const float* add, float* out,
                               int K, int Mpad, int Mreal, int N, int Z, int HIN,
                               int ksIn, int zsIn, int zsOut, int outMs, hipStream_t s) {
    constexpr int BM = 16 * TO;
    dim3 g((N + 127) / 128, Z, Mpad / BM);
    gemm_k<KH, PAD, TO, ADD, RELU><<<g, BLK, 0, s>>>(in, A, bias, add, out,
        K, Mpad, Mreal, N, HIN, ksIn, zsIn, zsOut, outMs);
}

// ======================= host =======================
extern "C" void kernel_launch(void* const* d_in, const int* in_sizes, int n_in,
                              void* d_out, int out_size, void* d_ws, size_t ws_size,
                              hipStream_t stream) {
    const float* x   = (const float*)d_in[0];
    const float* W0a = (const float*)d_in[1];  const float* b0a = (const float*)d_in[2];
    const float* Wl0 = (const float*)d_in[3];  const float* bl0 = (const float*)d_in[4];
    const float* W0b = (const float*)d_in[5];  const float* b0b = (const float*)d_in[6];
    const float* Wr0 = (const float*)d_in[7];  const float* br0 = (const float*)d_in[8];
    const float* W0c = (const float*)d_in[9];  const float* b0c = (const float*)d_in[10];
    const float* W1  = (const float*)d_in[11]; const float* b1  = (const float*)d_in[12];
    const float* Wl1 = (const float*)d_in[13]; const float* bl1 = (const float*)d_in[14];
    const float* W2  = (const float*)d_in[15]; const float* b2  = (const float*)d_in[16];
    const float* Wra = (const float*)d_in[17]; const float* bra = (const float*)d_in[18];
    const float* Wa  = (const float*)d_in[19]; const float* ba  = (const float*)d_in[20];
    const float* W3  = (const float*)d_in[21]; const float* b3  = (const float*)d_in[22];
    const float* Wl2 = (const float*)d_in[23]; const float* bl2 = (const float*)d_in[24];
    const float* W4  = (const float*)d_in[25]; const float* b4  = (const float*)d_in[26];
    const float* Wrb = (const float*)d_in[27]; const float* brb = (const float*)d_in[28];
    const float* Wb  = (const float*)d_in[29]; const float* bb  = (const float*)d_in[30];
    float* outp = (float*)d_out;

    const int B = in_sizes[0] / 635;   // 1024

    // ---- padded transposed-weight slots (floats)
    size_t cur = 0;
    auto alloc = [&](size_t f) { size_t o = cur; cur = (cur + f + 63) & ~(size_t)63; return o; };
    const size_t o_W0b = alloc(3 * 5 * 32),    o_W1  = alloc(3 * 25 * 80),
                 o_Wa  = alloc(1 * 25 * 160),  o_W2  = alloc(3 * 75 * 160),
                 o_W3  = alloc(2 * 150 * 320), o_W4  = alloc(2 * 300 * 512),
                 o_Wb  = alloc(3 * 150 * 512),
                 o_Wl0 = alloc(127 * 96),      o_Wl1 = alloc(81 * 48),
                 o_Wl2 = alloc(41 * 32),
                 o_Wr0 = alloc(127 * 96),      o_Wra = alloc(81 * 48),
                 o_Wrb = alloc(41 * 32);
    const size_t wt_end = cur;

    // ---- activation sizes (floats per batch element), CHWB layout
    static const size_t m[16] = {635, 3175, 2025, 405, 10125, 10125, 30375, 15375,
                                 5125, 30750, 30750, 49200, 21600, 13500, 27648, 27648};
    auto chunk_floats = [&](int cbx) -> size_t {
        size_t s = 0;
        for (int i = 0; i < 16; ++i) s += ((m[i] * (size_t)cbx) + 63) & ~(size_t)63;
        return s;
    };
    int CB = 0;
    for (int c = 1024; c >= 64; c >>= 1) {
        if (c > B || (B % c) != 0) continue;
        if ((wt_end + chunk_floats(c)) * 4 <= ws_size) { CB = c; break; }
    }
    if (!CB) return;
    const int cb = CB;

    float* wsf = (float*)d_ws;
    float* abase = wsf + wt_end;
    size_t c2 = 0;
    auto ab = [&](size_t f) { float* p = abase + c2; c2 = (c2 + f + 63) & ~(size_t)63; return p; };
    float *xt = ab(m[0]*cb),  *t0 = ab(m[1]*cb),  *t1 = ab(m[2]*cb),  *t3 = ab(m[3]*cb),
          *y0 = ab(m[4]*cb),  *x1 = ab(m[5]*cb),  *u0 = ab(m[6]*cb),  *u1 = ab(m[7]*cb),
          *u3 = ab(m[8]*cb),  *y1 = ab(m[9]*cb),  *x2 = ab(m[10]*cb), *v0 = ab(m[11]*cb),
          *v1 = ab(m[12]*cb), *v3 = ab(m[13]*cb), *y2 = ab(m[14]*cb), *v2 = ab(m[15]*cb);

    // ---- weight transforms (every call; ws is re-poisoned by harness)
    auto wt = [&](const float* src, size_t off, int O, int I, int KH, int Mpad) {
        int tot = KH * I * Mpad;
        wtrans_k<<<(tot + BLK - 1) / BLK, BLK, 0, stream>>>(src, wsf + off, O, I, KH, Mpad);
    };
    wt(W0b, o_W0b, 25, 5, 3, 32);     wt(W1, o_W1, 75, 25, 3, 80);
    wt(Wa, o_Wa, 150, 25, 1, 160);    wt(W2, o_W2, 150, 75, 3, 160);
    wt(W3, o_W3, 300, 150, 2, 320);   wt(W4, o_W4, 512, 300, 2, 512);
    wt(Wb, o_Wb, 512, 150, 3, 512);
    wt(Wl0, o_Wl0, 81, 127, 1, 96);   wt(Wl1, o_Wl1, 41, 81, 1, 48);
    wt(Wl2, o_Wl2, 18, 41, 1, 32);
    wt(Wr0, o_Wr0, 81, 127, 1, 96);   wt(Wra, o_Wra, 41, 81, 1, 48);
    wt(Wrb, o_Wrb, 18, 41, 1, 32);

    for (int b0 = 0; b0 < B; b0 += cb) {
        const int N127 = 127 * cb, N81 = 81 * cb, N41 = 41 * cb, N18 = 18 * cb;

        // x[b0..][635] -> xt [635][cb]
        {
            dim3 g((635 + 63) / 64, cb / 64);
            transpose_k<<<g, BLK, 0, stream>>>(x + (size_t)b0 * 635, xt, cb, 635);
        }
        // block 0
        conv0a_k<<<(N127 + BLK - 1) / BLK, BLK, 0, stream>>>(xt, W0a, b0a, t0, N127);
        gemm_launch<1,0,6,false,true >(t0, wsf + o_Wl0, bl0, nullptr, t1,
            127, 96, 81, cb, 25, 25, cb, N127, N81, cb, stream);
        gemm_launch<1,0,6,false,false>(xt, wsf + o_Wr0, br0, nullptr, t3,
            127, 96, 81, cb, 5, 5, cb, N127, N81, cb, stream);
        conv0c_k<<<(5 * N81 + BLK - 1) / BLK, BLK, 0, stream>>>(t3, W0c, b0c, y0, 5 * N81);
        gemm_launch<3,1,2,true ,false>(t1, wsf + o_W0b, b0b, y0, x1,
            5, 32, 25, N81, 5, 5, 5 * N81, N81, N81, 5 * N81, stream);
        // block 1
        gemm_launch<3,1,5,false,false>(x1, wsf + o_W1, b1, nullptr, u0,
            25, 80, 75, N81, 5, 5, 5 * N81, N81, N81, 5 * N81, stream);
        gemm_launch<1,0,3,false,true >(u0, wsf + o_Wl1, bl1, nullptr, u1,
            81, 48, 41, cb, 375, 375, cb, N81, N41, cb, stream);
        gemm_launch<1,0,3,false,false>(x1, wsf + o_Wra, bra, nullptr, u3,
            81, 48, 41, cb, 125, 125, cb, N81, N41, cb, stream);
        gemm_launch<1,0,5,false,false>(u3, wsf + o_Wa, ba, nullptr, y1,
            25, 160, 150, 5 * N41, 1, 1, 5 * N41, 0, 0, 5 * N41, stream);
        gemm_launch<3,1,5,true ,false>(u1, wsf + o_W2, b2, y1, x2,
            75, 160, 150, N41, 5, 5, 5 * N41, N41, N41, 5 * N41, stream);
        // block 2
        gemm_launch<2,0,5,false,false>(x2, wsf + o_W3, b3, nullptr, v0,
            150, 320, 300, N41, 4, 5, 5 * N41, N41, N41, 4 * N41, stream);
        gemm_launch<1,0,2,false,true >(v0, wsf + o_Wl2, bl2, nullptr, v1,
            41, 32, 18, cb, 1200, 1200, cb, N41, N18, cb, stream);
        gemm_launch<1,0,2,false,false>(x2, wsf + o_Wrb, brb, nullptr, v3,
            41, 32, 18, cb, 750, 750, cb, N41, N18, cb, stream);
        gemm_launch<3,0,8,false,false>(v3, wsf + o_Wb, bb, nullptr, y2,
            150, 512, 512, N18, 3, 5, 5 * N18, N18, N18, 3 * N18, stream);
        gemm_launch<2,0,8,true ,false>(v1, wsf + o_W4, b4, y2, v2,
            300, 512, 512, N18, 3, 4, 4 * N18, N18, N18, 3 * N18, stream);
        // v2 [27648][cb] -> out[b0..][27648]
        {
            dim3 g(cb / 64, 27648 / 64);
            transpose_k<<<g, BLK, 0, stream>>>(v2, outp + (size_t)b0 * 27648, 27648, cb);
        }
    }
}

// Round 5
// 1323.920 us; speedup vs baseline: 5.9273x; 2.1556x over previous
//
#include <hip/hip_runtime.h>
#include <cstddef>
#include <cstdint>

#define BLK 256
typedef unsigned short u16;
typedef __attribute__((ext_vector_type(8))) short s8v;   // 8 bf16 (4 VGPRs)
typedef __attribute__((ext_vector_type(4))) float f4v;   // 4 fp32 acc

__device__ __forceinline__ u16 f2bf(float f) {           // RNE float->bf16
    unsigned u = __float_as_uint(f);
    u += 0x7fffu + ((u >> 16) & 1u);
    return (u16)(u >> 16);
}

// ======================= fp32 weight panel: W[O][I][KH] -> Wt[KH][I][Mpad] =======================
__global__ void wtrans_k(const float* __restrict__ W, float* __restrict__ Wt,
                         int O, int I, int KH, int Mpad) {
    int idx = blockIdx.x * BLK + threadIdx.x;
    int total = KH * I * Mpad;
    if (idx >= total) return;
    int o = idx % Mpad;
    int r = idx / Mpad;
    int i = r % I;
    int dh = r / I;
    Wt[idx] = (o < O) ? W[(o * I + i) * KH + dh] : 0.f;
}

// ============ bf16 MFMA weight image: W[O][I][KH] -> img[dh][kt][mt][kg4][ml64][kl8] ============
__global__ void wtransm_k(const float* __restrict__ W, u16* __restrict__ img,
                          int O, int I, int KH, int Kpad, int Mpad) {
    int idx = blockIdx.x * BLK + threadIdx.x;
    int total = KH * Kpad * Mpad;
    if (idx >= total) return;
    const int nMT = Mpad >> 6, nKT = Kpad >> 5;
    int kl = idx & 7;
    int ml = (idx >> 3) & 63;
    int kg = (idx >> 9) & 3;
    int rest = idx >> 11;
    int mt = rest % nMT; rest /= nMT;
    int kt = rest % nKT;
    int dh = rest / nKT;
    int k = kt * 32 + kg * 8 + kl;
    int m = mt * 64 + ml;
    float v = (m < O && k < I) ? W[((size_t)m * I + k) * KH + dh] : 0.f;
    img[idx] = f2bf(v);
}

// ======================= generic transpose =======================
__global__ __launch_bounds__(256)
void transpose_k(const float* __restrict__ in, float* __restrict__ out, int P, int Q) {
    __shared__ float tile[64][65];
    const int p0 = blockIdx.y * 64, q0 = blockIdx.x * 64;
    const int j = threadIdx.x & 63, i4 = threadIdx.x >> 6;
#pragma unroll
    for (int ii = 0; ii < 16; ++ii) {
        int i = i4 + 4 * ii;
        int q = q0 + j;
        tile[i][j] = (q < Q) ? in[(size_t)(p0 + i) * Q + q] : 0.f;
    }
    __syncthreads();
#pragma unroll
    for (int ii = 0; ii < 16; ++ii) {
        int a = i4 + 4 * ii;
        if (q0 + a < Q) out[(size_t)(q0 + a) * P + p0 + j] = tile[j][a];
    }
}

// ======================= conv0a: I=1,KH=3,P=1,O=5 =======================
__global__ void conv0a_k(const float* __restrict__ xt, const float* __restrict__ W,
                         const float* __restrict__ bias, float* __restrict__ out, int N) {
    int n = blockIdx.x * BLK + threadIdx.x;
    if (n >= N) return;
    float xv[5];
#pragma unroll
    for (int h = 0; h < 5; ++h) xv[h] = xt[(size_t)h * N + n];
#pragma unroll
    for (int o = 0; o < 5; ++o) {
        float w0 = W[o * 3 + 0], w1 = W[o * 3 + 1], w2 = W[o * 3 + 2];
        float bv = bias[o];
#pragma unroll
        for (int h = 0; h < 5; ++h) {
            float acc = bv + w1 * xv[h];
            if (h > 0) acc += w0 * xv[h - 1];
            if (h < 4) acc += w2 * xv[h + 1];
            out[((size_t)o * 5 + h) * N + n] = acc;
        }
    }
}

// ======================= conv0c: 1x1, I=1 -> O=25 =======================
__global__ void conv0c_k(const float* __restrict__ in, const float* __restrict__ W,
                         const float* __restrict__ bias, float* __restrict__ out, int N5) {
    int idx = blockIdx.x * BLK + threadIdx.x;
    if (idx >= N5) return;
    float v = in[idx];
#pragma unroll
    for (int o = 0; o < 25; ++o)
        out[(size_t)o * N5 + idx] = W[o] * v + bias[o];
}

// ======================= fp32 GEMM (small convs + semi-linears) =======================
// out[m][z][n] = sum_dh sum_k A[dh][k][m] * in[k*ksIn + hp*zsIn + n], hp = z+dh-PAD
// PK=0: plain fp32 out. PK=1: also k8-pack bf16 (m=channel): (m/8)*pkS0 + z*pkS1 + n*8 + m%8
// PK=2: k8-pack bf16 with z=(c,h), c=z/pkAux: (c/8)*pkS0 + h*pkS1 + (m*N+n)*8 + c%8
template<int KH, int PAD, int TO, bool ADD, bool RELU, int PK, bool WF>
__global__ __launch_bounds__(256)
void gemm_k(const float* __restrict__ in, const float* __restrict__ A,
            const float* __restrict__ bias, const float* __restrict__ add,
            float* __restrict__ out, u16* __restrict__ outb,
            long pkS0, long pkS1, int pkAux,
            int K, int Mpad, int Mreal, int N, int HIN,
            int ksIn, int zsIn, int zsOut, int outMs) {
    constexpr int BM = 16 * TO;
    constexpr int BN = 128;
    constexpr int IC = 8;
    __shared__ __align__(16) float Xs[IC][BN];
    __shared__ __align__(16) float As[IC][BM];
    const int n0 = blockIdx.x * BN;
    const int z  = blockIdx.y;
    const int m0 = blockIdx.z * BM;
    const int t  = threadIdx.x;
    const int tn = t & 15, to = t >> 4;
    const bool fullN = (n0 + BN <= N);

    const int xk = t >> 5;
    const int xj = (t & 31) * 4;
    constexpr int AV = IC * BM / 4;
    const int ak = t / (BM / 4);
    const int aj = (t % (BM / 4)) * 4;

    float acc[TO][8];
#pragma unroll
    for (int a = 0; a < TO; ++a)
#pragma unroll
        for (int j = 0; j < 8; ++j) acc[a][j] = 0.f;

#pragma unroll
    for (int dh = 0; dh < KH; ++dh) {
        const int hp = z + dh - PAD;
        if (hp < 0 || hp >= HIN) continue;
        const float* __restrict__ inz = in + (size_t)hp * zsIn;
        const float* __restrict__ Ad  = A + (size_t)dh * K * Mpad;
        for (int k0 = 0; k0 < K; k0 += IC) {
            __syncthreads();
            {
                const int k = k0 + xk;
                float4 v = make_float4(0.f, 0.f, 0.f, 0.f);
                if (k < K) {
                    const float* p = inz + (size_t)k * ksIn + n0 + xj;
                    if (fullN) v = *(const float4*)p;
                    else {
                        float tmp[4] = {0.f, 0.f, 0.f, 0.f};
#pragma unroll
                        for (int u = 0; u < 4; ++u)
                            if (n0 + xj + u < N) tmp[u] = p[u];
                        v = make_float4(tmp[0], tmp[1], tmp[2], tmp[3]);
                    }
                }
                *(float4*)&Xs[xk][xj] = v;
            }
            if (t < AV) {
                const int k = k0 + ak;
                float4 v = make_float4(0.f, 0.f, 0.f, 0.f);
                if (k < K) v = *(const float4*)(Ad + (size_t)k * Mpad + m0 + aj);
                *(float4*)&As[ak][aj] = v;
            }
            __syncthreads();
#pragma unroll
            for (int kk = 0; kk < IC; ++kk) {
                float xr[8];
                *(float4*)&xr[0] = *(const float4*)&Xs[kk][tn * 4];
                *(float4*)&xr[4] = *(const float4*)&Xs[kk][64 + tn * 4];
                float ar[TO];
                if constexpr (TO % 4 == 0) {
#pragma unroll
                    for (int g = 0; g < TO / 4; ++g)
                        *(float4*)&ar[g * 4] = *(const float4*)&As[kk][g * 64 + to * 4];
                } else {
#pragma unroll
                    for (int a = 0; a < TO; ++a) ar[a] = As[kk][to + 16 * a];
                }
#pragma unroll
                for (int a = 0; a < TO; ++a)
#pragma unroll
                    for (int j = 0; j < 8; ++j)
                        acc[a][j] = fmaf(ar[a], xr[j], acc[a][j]);
            }
        }
    }

    const size_t zo = (size_t)z * zsOut + n0;
    if constexpr (PK == 0) {
#pragma unroll
        for (int a = 0; a < TO; ++a) {
            int mi;
            if constexpr (TO % 4 == 0) mi = m0 + (a / 4) * 64 + to * 4 + (a % 4);
            else mi = m0 + to + 16 * a;
            if (mi >= Mreal) continue;
            const float bv = bias[mi];
            const size_t rb = (size_t)mi * outMs + zo;
#pragma unroll
            for (int jj = 0; jj < 2; ++jj) {
                const int nb = jj * 64 + tn * 4;
                float v[4];
#pragma unroll
                for (int u = 0; u < 4; ++u) v[u] = acc[a][jj * 4 + u] + bv;
                if (fullN) {
                    if (ADD) {
                        float4 w = *(const float4*)(add + rb + nb);
                        v[0] += w.x; v[1] += w.y; v[2] += w.z; v[3] += w.w;
                    }
                    if (RELU)
#pragma unroll
                        for (int u = 0; u < 4; ++u) v[u] = fmaxf(v[u], 0.f);
                    *(float4*)(out + rb + nb) = make_float4(v[0], v[1], v[2], v[3]);
                } else {
#pragma unroll
                    for (int u = 0; u < 4; ++u) {
                        if (n0 + nb + u < N) {
                            float vv = v[u];
                            if (ADD) vv += add[rb + nb + u];
                            if (RELU) vv = fmaxf(vv, 0.f);
                            out[rb + nb + u] = vv;
                        }
                    }
                }
            }
        }
    } else {
        const int pc = (PK == 2) ? z / pkAux : 0;
        const int ph = (PK == 2) ? z - pc * pkAux : 0;
#pragma unroll
        for (int a = 0; a < TO; ++a) {
            int mi;
            if constexpr (TO % 4 == 0) mi = m0 + (a / 4) * 64 + to * 4 + (a % 4);
            else mi = m0 + to + 16 * a;
            const bool mok = mi < Mreal;
            const float bv = mok ? bias[mi] : 0.f;
            const size_t rb = (size_t)mi * outMs + zo;
#pragma unroll
            for (int jj = 0; jj < 2; ++jj)
#pragma unroll
            for (int u = 0; u < 4; ++u) {
                const int nb = jj * 64 + tn * 4 + u;
                if (n0 + nb >= N) continue;
                float v = 0.f;
                if (mok) {
                    v = acc[a][jj * 4 + u] + bv;
                    if (ADD) v += add[rb + nb];
                    if (RELU) v = fmaxf(v, 0.f);
                    if (WF) out[rb + nb] = v;
                }
                const u16 hv = f2bf(v);
                if constexpr (PK == 1) {
                    outb[(long)(mi >> 3) * pkS0 + (long)z * pkS1 + (long)(n0 + nb) * 8 + (mi & 7)] = hv;
                } else {
                    if (mok)
                        outb[(long)(pc >> 3) * pkS0 + (long)ph * pkS1 + ((long)mi * N + n0 + nb) * 8 + (pc & 7)] = hv;
                }
            }
        }
    }
}

template<int KH, int PAD, int TO, bool ADD, bool RELU, int PK, bool WF>
static inline void gemm_launch(const float* in, const float* A, const float* bias,
                               const float* add, float* out, u16* outb,
                               long pkS0, long pkS1, int pkAux,
                               int K, int Mpad, int Mreal, int N, int Z, int HIN,
                               int ksIn, int zsIn, int zsOut, int outMs, hipStream_t s) {
    constexpr int BM = 16 * TO;
    dim3 g((N + 127) / 128, Z, Mpad / BM);
    gemm_k<KH, PAD, TO, ADD, RELU, PK, WF><<<g, BLK, 0, s>>>(in, A, bias, add, out, outb,
        pkS0, pkS1, pkAux, K, Mpad, Mreal, N, HIN, ksIn, zsIn, zsOut, outMs);
}

// ======================= MFMA conv =======================
// inb: k8-packed bf16 activations: (c/8)*HIN*N*8 + h*N*8 + n*8 + c%8
// Aimg: weight image [dh][kt][mt][kg4][ml64][kl8] bf16
// out fp32 [M][HOUT][N]; ADD: in-place accumulate (out pre-filled); WBF: also k8-pack bf16.
template<int KH, int PAD, bool ADD, bool WBF>
__global__ __launch_bounds__(256)
void mconv_k(const u16* __restrict__ inb, const u16* __restrict__ Aimg,
             const float* __restrict__ bias, float* __restrict__ out,
             u16* __restrict__ outb,
             int Kpad, int Mpad, int Mreal, int N, int HIN,
             long pkS0, long pkS1, int pkMax) {
    const int HOUT = HIN - KH + 1 + 2 * PAD;
    __shared__ __align__(16) u16 As[2048];   // 4 kg x 64 m x 8
    __shared__ __align__(16) u16 Xs[4096];   // 4 kg x 128 n x 8
    const int n0 = blockIdx.x * 128;
    const int z  = blockIdx.y;
    const int mt = blockIdx.z;
    const int t  = threadIdx.x;
    const int lane = t & 63, w = t >> 6;
    const int wm = w & 1, wn = w >> 1;
    const int c15 = lane & 15, g = lane >> 4;
    const int nKT = Kpad >> 5, nMT = Mpad >> 6;
    const long kgS0 = (long)HIN * N * 8;
    const long kgS1 = (long)N * 8;

    f4v acc[2][4] = {};

    const int aoff0 = (g * 64 + wm * 32 + c15) * 8;
    const int aoff1 = aoff0 + 16 * 8;
    int xoff[4];
#pragma unroll
    for (int nf = 0; nf < 4; ++nf) xoff[nf] = (g * 128 + wn * 64 + nf * 16 + c15) * 8;

#pragma unroll
    for (int dh = 0; dh < KH; ++dh) {
        const int hp = z + dh - PAD;
        if (hp < 0 || hp >= HIN) continue;
        for (int kt = 0; kt < nKT; ++kt) {
            __syncthreads();
            {
                const u16* ga = Aimg + (((long)(dh * nKT + kt) * nMT + mt) << 11) + t * 8;
                *(s8v*)&As[t * 8] = *(const s8v*)ga;
            }
#pragma unroll
            for (int p = 0; p < 2; ++p) {
                const int idx = p * 256 + t;
                const int kg = idx >> 7, nl = idx & 127;
                const u16* gx = inb + (long)(kt * 4 + kg) * kgS0 + (long)hp * kgS1 + (long)(n0 + nl) * 8;
                *(s8v*)&Xs[idx * 8] = *(const s8v*)gx;
            }
            __syncthreads();
            s8v af0 = *(const s8v*)&As[aoff0];
            s8v af1 = *(const s8v*)&As[aoff1];
#pragma unroll
            for (int nf = 0; nf < 4; ++nf) {
                s8v xf = *(const s8v*)&Xs[xoff[nf]];
                acc[0][nf] = __builtin_amdgcn_mfma_f32_16x16x32_bf16(af0, xf, acc[0][nf], 0, 0, 0);
                acc[1][nf] = __builtin_amdgcn_mfma_f32_16x16x32_bf16(af1, xf, acc[1][nf], 0, 0, 0);
            }
        }
    }

    const long outMs = (long)HOUT * N;
    const long zN = (long)z * N;
#pragma unroll
    for (int mf = 0; mf < 2; ++mf)
#pragma unroll
    for (int r = 0; r < 4; ++r) {
        const int m = mt * 64 + wm * 32 + mf * 16 + g * 4 + r;
        const bool mok = m < Mreal;
        const float bv = mok ? bias[m] : 0.f;
        const long rb = (long)m * outMs + zN;
#pragma unroll
        for (int nf = 0; nf < 4; ++nf) {
            const int n = n0 + wn * 64 + nf * 16 + c15;
            float v = acc[mf][nf][r] + bv;
            if (mok) {
                if (ADD) v += out[rb + n];
                out[rb + n] = v;
            }
            if (WBF) {
                if (m < pkMax)
                    outb[(long)(m >> 3) * pkS0 + (long)z * pkS1 + (long)n * 8 + (m & 7)] = f2bf(mok ? v : 0.f);
            }
        }
    }
}

// ======================= host =======================
extern "C" void kernel_launch(void* const* d_in, const int* in_sizes, int n_in,
                              void* d_out, int out_size, void* d_ws, size_t ws_size,
                              hipStream_t stream) {
    const float* x   = (const float*)d_in[0];
    const float* W0a = (const float*)d_in[1];  const float* b0a = (const float*)d_in[2];
    const float* Wl0 = (const float*)d_in[3];  const float* bl0 = (const float*)d_in[4];
    const float* W0b = (const float*)d_in[5];  const float* b0b = (const float*)d_in[6];
    const float* Wr0 = (const float*)d_in[7];  const float* br0 = (const float*)d_in[8];
    const float* W0c = (const float*)d_in[9];  const float* b0c = (const float*)d_in[10];
    const float* W1  = (const float*)d_in[11]; const float* b1  = (const float*)d_in[12];
    const float* Wl1 = (const float*)d_in[13]; const float* bl1 = (const float*)d_in[14];
    const float* W2  = (const float*)d_in[15]; const float* b2  = (const float*)d_in[16];
    const float* Wra = (const float*)d_in[17]; const float* bra = (const float*)d_in[18];
    const float* Wa  = (const float*)d_in[19]; const float* ba  = (const float*)d_in[20];
    const float* W3  = (const float*)d_in[21]; const float* b3  = (const float*)d_in[22];
    const float* Wl2 = (const float*)d_in[23]; const float* bl2 = (const float*)d_in[24];
    const float* W4  = (const float*)d_in[25]; const float* b4  = (const float*)d_in[26];
    const float* Wrb = (const float*)d_in[27]; const float* brb = (const float*)d_in[28];
    const float* Wb  = (const float*)d_in[29]; const float* bb  = (const float*)d_in[30];
    float* outp = (float*)d_out;

    const int B = in_sizes[0] / 635;   // 1024

    // ---- weight region (float units)
    size_t cur = 0;
    auto al = [&](size_t f) { size_t o = cur; cur = (cur + f + 63) & ~(size_t)63; return o; };
    const size_t o_W0b = al(480),    o_Wa  = al(4000),
                 o_Wl0 = al(12192),  o_Wl1 = al(3888),  o_Wl2 = al(1312),
                 o_Wr0 = al(12192),  o_Wra = al(3888),  o_Wrb = al(1312);
    const size_t o_M1 = al(6144), o_M2 = al(27648), o_M3 = al(51200),
                 o_Mb = al(122880), o_M4 = al(163840);
    const size_t wt_end = cur;

    // ---- aliased activation slots (floats per batch element)
    // S1: xt(635)/u0(30375)/v0(49200)        = 49200
    // S2: t0(3175)/u3(5125)/y2+v2(27648)     = 27648
    // S3: t1(2025)/x2_bf(16400)              = 16400
    // S4: t3(405)/u1_bf(9840)/v3_bf(7200)    = 9840
    // S5: y0(10125)/x2incl y1(30750)         = 30750
    // S6: x1(10125)+x1_bf(6480) / v1_bf(11520) = 16605
    const size_t TOT = 150443;
    int cb = 0;
    for (int c = 1024; c >= 256; c >>= 1)
        if ((wt_end + TOT * (size_t)c) * 4 <= ws_size) { cb = c; break; }
    if (!cb) return;

    float* wsf = (float*)d_ws;
    float* ab = wsf + wt_end;
    float* S1 = ab;
    float* S2 = ab + (size_t)49200 * cb;
    float* S3 = ab + (size_t)76848 * cb;
    float* S4 = ab + (size_t)93248 * cb;
    float* S5 = ab + (size_t)103088 * cb;
    float* S6 = ab + (size_t)133838 * cb;
    float *xt = S1, *u0 = S1, *v0 = S1;
    float *t0 = S2, *u3 = S2, *yv2 = S2;
    float *t1 = S3;  u16* x2b = (u16*)S3;
    float *t3 = S4;  u16* u1b = (u16*)S4;  u16* v3b = (u16*)S4;
    float *y0 = S5, *x2 = S5;
    float *x1 = S6;  u16* x1b = (u16*)(S6 + (size_t)10125 * cb);  u16* v1b = (u16*)S6;

    // ---- weight transforms (every call)
    auto wtp = [&](const float* src, size_t off, int O, int I, int KH, int Mpad) {
        int tot = KH * I * Mpad;
        wtrans_k<<<(tot + 255) / 256, BLK, 0, stream>>>(src, wsf + off, O, I, KH, Mpad);
    };
    wtp(W0b, o_W0b, 25, 5, 3, 32);    wtp(Wa, o_Wa, 150, 25, 1, 160);
    wtp(Wl0, o_Wl0, 81, 127, 1, 96);  wtp(Wl1, o_Wl1, 41, 81, 1, 48);
    wtp(Wl2, o_Wl2, 18, 41, 1, 32);   wtp(Wr0, o_Wr0, 81, 127, 1, 96);
    wtp(Wra, o_Wra, 41, 81, 1, 48);   wtp(Wrb, o_Wrb, 18, 41, 1, 32);
    auto wtm = [&](const float* src, size_t off, int O, int I, int KH, int Kpad, int Mpad) {
        int tot = KH * Kpad * Mpad;
        wtransm_k<<<(tot + 255) / 256, BLK, 0, stream>>>(src, (u16*)(wsf + off), O, I, KH, Kpad, Mpad);
    };
    wtm(W1, o_M1,  75,  25, 3,  32, 128);
    wtm(W2, o_M2, 150,  75, 3,  96, 192);
    wtm(W3, o_M3, 300, 150, 2, 160, 320);
    wtm(Wb, o_Mb, 512, 150, 3, 160, 512);
    wtm(W4, o_M4, 512, 300, 2, 320, 512);

    for (int b0 = 0; b0 < B; b0 += cb) {
        const int N127 = 127 * cb, N81 = 81 * cb, N41 = 41 * cb, N18 = 18 * cb;

        { dim3 g((635 + 63) / 64, cb / 64);
          transpose_k<<<g, BLK, 0, stream>>>(x + (size_t)b0 * 635, xt, cb, 635); }
        conv0a_k<<<(N127 + 255) / 256, BLK, 0, stream>>>(xt, W0a, b0a, t0, N127);
        gemm_launch<1,0,6,false,true ,0,true>(t0, wsf + o_Wl0, bl0, nullptr, t1, nullptr, 0, 0, 0,
            127, 96, 81, cb, 25, 25, cb, N127, N81, cb, stream);
        gemm_launch<1,0,6,false,false,0,true>(xt, wsf + o_Wr0, br0, nullptr, t3, nullptr, 0, 0, 0,
            127, 96, 81, cb, 5, 5, cb, N127, N81, cb, stream);
        conv0c_k<<<(5 * N81 + 255) / 256, BLK, 0, stream>>>(t3, W0c, b0c, y0, 5 * N81);
        gemm_launch<3,1,2,true ,false,1,true>(t1, wsf + o_W0b, b0b, y0, x1, x1b,
            (long)5 * N81 * 8, (long)N81 * 8, 0,
            5, 32, 25, N81, 5, 5, 5 * N81, N81, N81, 5 * N81, stream);
        { dim3 g(N81 / 128, 5, 2);
          mconv_k<3,1,false,false><<<g, BLK, 0, stream>>>(x1b, (u16*)(wsf + o_M1), b1, u0, nullptr,
              32, 128, 75, N81, 5, 0, 0, 0); }
        hipMemsetAsync(u1b, 0, (size_t)19680 * cb * 2, stream);
        gemm_launch<1,0,3,false,true ,2,false>(u0, wsf + o_Wl1, bl1, nullptr, nullptr, u1b,
            (long)5 * N41 * 8, (long)N41 * 8, 5,
            81, 48, 41, cb, 375, 375, cb, N81, N41, cb, stream);
        gemm_launch<1,0,3,false,false,0,true>(x1, wsf + o_Wra, bra, nullptr, u3, nullptr, 0, 0, 0,
            81, 48, 41, cb, 125, 125, cb, N81, N41, cb, stream);
        gemm_launch<1,0,5,false,false,0,true>(u3, wsf + o_Wa, ba, nullptr, x2, nullptr, 0, 0, 0,
            25, 160, 150, 5 * N41, 1, 1, 5 * N41, 0, 0, 5 * N41, stream);
        { dim3 g(N41 / 128, 5, 3);
          mconv_k<3,1,true,true><<<g, BLK, 0, stream>>>(u1b, (u16*)(wsf + o_M2), b2, x2, x2b,
              96, 192, 150, N41, 5, (long)5 * N41 * 8, (long)N41 * 8, 160); }
        { dim3 g(N41 / 128, 4, 5);
          mconv_k<2,0,false,false><<<g, BLK, 0, stream>>>(x2b, (u16*)(wsf + o_M3), b3, v0, nullptr,
              160, 320, 300, N41, 5, 0, 0, 0); }
        hipMemsetAsync(v1b, 0, (size_t)23040 * cb * 2, stream);
        gemm_launch<1,0,2,false,true ,2,false>(v0, wsf + o_Wl2, bl2, nullptr, nullptr, v1b,
            (long)4 * N18 * 8, (long)N18 * 8, 4,
            41, 32, 18, cb, 1200, 1200, cb, N41, N18, cb, stream);
        hipMemsetAsync(v3b, 0, (size_t)14400 * cb * 2, stream);
        gemm_launch<1,0,2,false,false,2,false>(x2, wsf + o_Wrb, brb, nullptr, nullptr, v3b,
            (long)5 * N18 * 8, (long)N18 * 8, 5,
            41, 32, 18, cb, 750, 750, cb, N41, N18, cb, stream);
        { dim3 g(N18 / 128, 3, 8);
          mconv_k<3,0,false,false><<<g, BLK, 0, stream>>>(v3b, (u16*)(wsf + o_Mb), bb, yv2, nullptr,
              160, 512, 512, N18, 5, 0, 0, 0); }
        { dim3 g(N18 / 128, 3, 8);
          mconv_k<2,0,true,false><<<g, BLK, 0, stream>>>(v1b, (u16*)(wsf + o_M4), b4, yv2, nullptr,
              320, 512, 512, N18, 4, 0, 0, 0); }
        { dim3 g(cb / 64, 27648 / 64);
          transpose_k<<<g, BLK, 0, stream>>>(yv2, outp + (size_t)b0 * 27648, 27648, cb); }
    }
}